// Round 13
// baseline (239.184 us; speedup 1.0000x reference)
//
#include <hip/hip_runtime.h>
#include <stdint.h>

typedef __attribute__((ext_vector_type(4))) float f32x4;
typedef __attribute__((ext_vector_type(8))) short short8v;
typedef __attribute__((ext_vector_type(4))) unsigned short ushort4v;

#define DEV __device__ __forceinline__
#define EXP2 __builtin_amdgcn_exp2f
#define WAITVM0 asm volatile("s_waitcnt vmcnt(0)" ::: "memory")
#define WAITVM2 asm volatile("s_waitcnt vmcnt(2)" ::: "memory")
#define WAITVM4 asm volatile("s_waitcnt vmcnt(4)" ::: "memory")
#define FENCE   asm volatile("" ::: "memory")
#define BARRIER __builtin_amdgcn_s_barrier()

DEV unsigned short f2bf(float x) {
    union { float f; uint32_t u; } v; v.f = x;
    uint32_t r = v.u + 0x7fffu + ((v.u >> 16) & 1u);
    return (unsigned short)(r >> 16);
}
DEV float bf2f(unsigned short h) {
    union { uint32_t u; float f; } v; v.u = ((uint32_t)h) << 16;
    return v.f;
}
DEV uint32_t cvtpk(float lo, float hi) {
    uint32_t r;
    asm("v_cvt_pk_bf16_f32 %0, %1, %2" : "=v"(r) : "v"(lo), "v"(hi));
    return r;
}
DEV f32x4 mfma16(short8v a, short8v b, f32x4 c) {
    return __builtin_amdgcn_mfma_f32_16x16x32_bf16(a, b, c, 0, 0, 0);
}
DEV void gload16(const unsigned short* g, unsigned short* l) {
    __builtin_amdgcn_global_load_lds(
        (const __attribute__((address_space(1))) unsigned int*)g,
        (__attribute__((address_space(3))) unsigned int*)l, 16, 0, 0);
}
DEV void ntstore4(float* p, f32x4 v) { __builtin_nontemporal_store(v, (f32x4*)p); }

// ---------------- prep: fp32 -> bf16 (all three inputs, one launch) ----------------
__global__ void k_cvt3(const float* __restrict__ a, unsigned short* __restrict__ oa, int na4,
                       const float* __restrict__ b, unsigned short* __restrict__ ob, int nb4,
                       const float* __restrict__ c, unsigned short* __restrict__ oc, int nc4) {
    int i = blockIdx.x * blockDim.x + threadIdx.x;
    const float* in; unsigned short* out; int idx;
    if (i < na4) { in = a; out = oa; idx = i; }
    else if (i < na4 + nb4) { in = b; out = ob; idx = i - na4; }
    else { idx = i - na4 - nb4; if (idx >= nc4) return; in = c; out = oc; }
    f32x4 v = *(const f32x4*)(in + (size_t)idx * 4);
    ushort4v h;
#pragma unroll
    for (int j = 0; j < 4; ++j) h[j] = f2bf(v[j]);
    *(ushort4v*)(out + (size_t)idx * 4) = h;
}

// ---------------- m97-style bf16 GEMM core (128x128 tile, gload_lds, dbuf) ---------
template <int KDIM>
DEV void gemm_core(const unsigned short* __restrict__ APTR,
                   const unsigned short* __restrict__ BPTR,
                   f32x4 (&acc)[4][4]) {
    __shared__ __align__(16) unsigned short As[2][128 * 32], Bs[2][128 * 32];
    int tid = threadIdx.x, lane = tid & 63, w = tid >> 6;
    int bm = blockIdx.x, bn = blockIdx.y;
    int wr = (w >> 1) * 64, wc = (w & 1) * 64;
    int lrow = lane & 15, lseg = lane >> 4;
#pragma unroll
    for (int m = 0; m < 4; ++m)
#pragma unroll
        for (int n = 0; n < 4; ++n) acc[m][n] = (f32x4){0.f, 0.f, 0.f, 0.f};
    auto STAGE = [&](int buf, int k0) {
#pragma unroll
        for (int i = 0; i < 2; ++i) {
            int ch = i * 256 + tid;
            int row = ch >> 2, seg = ch & 3;
            gload16(APTR + (size_t)(bm * 128 + row) * KDIM + k0 + seg * 8,
                    &As[buf][(i * 256 + (tid & ~63)) * 8]);
            gload16(BPTR + (size_t)(bn * 128 + row) * KDIM + k0 + seg * 8,
                    &Bs[buf][(i * 256 + (tid & ~63)) * 8]);
        }
    };
    const int NT = KDIM / 32;
    STAGE(0, 0);
    for (int t = 0; t < NT; ++t) {
        if (t < NT - 1) { STAGE((t + 1) & 1, (t + 1) * 32); WAITVM4; } else WAITVM0;
        BARRIER;
        const unsigned short* as = As[t & 1];
        const unsigned short* bs = Bs[t & 1];
        short8v fa[4], fb[4];
#pragma unroll
        for (int m = 0; m < 4; ++m) {
            fa[m] = *(const short8v*)(as + (wr + m * 16 + lrow) * 32 + lseg * 8);
            fb[m] = *(const short8v*)(bs + (wc + m * 16 + lrow) * 32 + lseg * 8);
        }
#pragma unroll
        for (int m = 0; m < 4; ++m)
#pragma unroll
            for (int n = 0; n < 4; ++n)
                acc[m][n] = mfma16(fa[m], fb[n], acc[m][n]);
        FENCE; BARRIER;
    }
}

// ---------------- K1: qkv = x @ Wqkv^T + b ------------------------------------------
// bn<16: Q/K columns -> QKVB (bf16). bn in [16,24): V columns -> transposed directly
// to VT[bh][e][c] via LDS (prep_v kernel eliminated; V never written to QKVB).
__global__ __launch_bounds__(256) void k_gemm_qkv(
    const unsigned short* __restrict__ XB, const unsigned short* __restrict__ WB,
    const float* __restrict__ BIAS, unsigned short* __restrict__ QKVB,
    unsigned short* __restrict__ VT) {
    __shared__ __align__(16) unsigned short tbuf[64][136];   // [e-half][c], pad 136
    f32x4 acc[4][4];
    gemm_core<1024>(XB, WB, acc);
    int tid = threadIdx.x, lane = tid & 63, w = tid >> 6;
    int bm = blockIdx.x, bn = blockIdx.y;
    int wr = (w >> 1) * 64, wc = (w & 1) * 64;
    int lrow = lane & 15, lseg = lane >> 4;
    if (bn < 16) {
        const int N = 3072;
#pragma unroll
        for (int n = 0; n < 4; ++n) {
            int col = bn * 128 + wc + n * 16 + lrow;
            float bv = BIAS[col];
#pragma unroll
            for (int m = 0; m < 4; ++m) {
                int row = bm * 128 + wr + m * 16 + lseg * 4;
#pragma unroll
                for (int i = 0; i < 4; ++i)
                    QKVB[(size_t)(row + i) * N + col] = f2bf(acc[m][n][i] + bv);
            }
        }
    } else {
        int b = bm >> 4, c0blk = (bm & 15) * 128;
        int h2 = (bn - 16) * 2;                      // two heads per block
#pragma unroll
        for (int hh = 0; hh < 2; ++hh) {
            if ((w & 1) == hh) {                     // waves owning this col-half
#pragma unroll
                for (int n = 0; n < 4; ++n) {
                    int cl = n * 16 + lrow;          // e within half (0..63)
                    float bv = BIAS[bn * 128 + wc + n * 16 + lrow];
#pragma unroll
                    for (int m = 0; m < 4; ++m) {
                        int row = wr + m * 16 + lseg * 4;
                        ushort4v tv;
#pragma unroll
                        for (int i = 0; i < 4; ++i) tv[i] = f2bf(acc[m][n][i] + bv);
                        *(ushort4v*)&tbuf[cl][row] = tv;
                    }
                }
            }
            __syncthreads();
            {
                int e = tid >> 2, cseg = (tid & 3) * 32;
                const unsigned short* tr = &tbuf[e][cseg];
                unsigned short* vp =
                    VT + ((size_t)((b * 16 + h2 + hh) * 64 + e)) * 2048 + c0blk + cseg;
#pragma unroll
                for (int q = 0; q < 4; ++q)
                    *(short8v*)(vp + q * 8) = *(const short8v*)(tr + q * 8);
            }
            __syncthreads();
        }
    }
}

// ---------------- K3: out = z @ Wout^T + b (fp32 out, nt stores) -------------------
__global__ __launch_bounds__(256) void k_gemm_out(
    const unsigned short* __restrict__ ZB, const unsigned short* __restrict__ WOB,
    const float* __restrict__ BIAS, float* __restrict__ OUT) {
    f32x4 acc[4][4];
    gemm_core<1024>(ZB, WOB, acc);
    int tid = threadIdx.x, lane = tid & 63, w = tid >> 6;
    int bm = blockIdx.x, bn = blockIdx.y;
    int wr = (w >> 1) * 64, wc = (w & 1) * 64;
    int lrow = lane & 15, lseg = lane >> 4;
    const int N = 1024;
#pragma unroll
    for (int n = 0; n < 4; ++n) {
        int col = bn * 128 + wc + n * 16 + lrow;
        float bv = BIAS[col];
#pragma unroll
        for (int m = 0; m < 4; ++m) {
            int row = bm * 128 + wr + m * 16 + lseg * 4;
#pragma unroll
            for (int i = 0; i < 4; ++i)
                __builtin_nontemporal_store(acc[m][n][i] + bv,
                                            OUT + (size_t)(row + i) * N + col);
        }
    }
}

// ---------------- K2: fused causal attention (8 waves, 128 rows/block) -------------
// pass A: 128-col K tiles (2x16KB dbuf); pass B: 64-col K+V tiles in same 32KB LDS
__global__ __launch_bounds__(512) void k_attn(
    const unsigned short* __restrict__ QKVB, const unsigned short* __restrict__ VT,
    float* __restrict__ ATTN, unsigned short* __restrict__ Z) {
    __shared__ __align__(16) unsigned short KV[2][8192];     // A: K[128][64]; B: K[64][64]+V[64][64]
    __shared__ __align__(16) float Pl[8][16][68];            // per-wave P relayout

    const float SCALE = 0.18033688011112042f;  // log2(e)/8 ; softmax in base-2
    int blk = blockIdx.x;
    int bh = blk & 31;
    int rtp = blk >> 5;                        // 0..15
    int rt = (rtp < 8) ? (15 - rtp) : (rtp - 8);  // heavy/light interleave for balance
    int b = bh >> 4, h = bh & 15;
    int tid = threadIdx.x, lane = tid & 63, w = tid >> 6;
    int lrow = lane & 15, lseg = lane >> 4;
    int r0 = rt * 128 + w * 16;
    int T = 2 * rt + 2;                        // pass-B 64-col tiles
    int Tw = (r0 >> 6) + 1;                    // this wave's causal 64-col tile count

    // Q fragments (bf16, rescaled by SCALE): A[m=r0+lrow][k=kc*32+lseg*8+j]
    short8v qf[2];
    {
        const unsigned short* qp =
            QKVB + (size_t)(b * 2048 + r0 + lrow) * 3072 + h * 64 + lseg * 8;
#pragma unroll
        for (int kc = 0; kc < 2; ++kc) {
            short8v qr = *(const short8v*)(qp + kc * 32);
            short8v qs;
#pragma unroll
            for (int j = 0; j < 8; ++j)
                qs[j] = (short)f2bf(bf2f((unsigned short)qr[j]) * SCALE);
            qf[kc] = qs;
        }
    }

    // ---------------- pass A: row sums over 128-col tiles --------------------------
    auto STAGEKA = [&](int buf, int t) {       // 128 keys x 64e
        const size_t kbase = ((size_t)b * 2048 + (size_t)t * 128) * 3072 + 1024 + h * 64;
#pragma unroll
        for (int i2 = 0; i2 < 2; ++i2) {
            int ch = i2 * 512 + tid;
            int c = ch >> 3, u = ch & 7, us = u ^ (c & 7);
            gload16(QKVB + kbase + (size_t)c * 3072 + us * 8,
                    &KV[buf][(i2 * 512 + (tid & ~63)) * 8]);
        }
    };
    float ls4[4] = {0.f, 0.f, 0.f, 0.f};
    int TA = rt + 1;
    STAGEKA(0, 0);
    for (int t = 0; t < TA; ++t) {
        if (t < TA - 1) { STAGEKA((t + 1) & 1, t + 1); WAITVM2; } else WAITVM0;
        BARRIER;
        const unsigned short* kb = KV[t & 1];
        f32x4 sc[8];
#pragma unroll
        for (int g = 0; g < 8; ++g) sc[g] = (f32x4){0.f, 0.f, 0.f, 0.f};
#pragma unroll
        for (int kc = 0; kc < 2; ++kc) {
            int uoff = (((kc * 4 + lseg) ^ (lrow & 7)) << 3);
#pragma unroll
            for (int g = 0; g < 8; ++g) {
                short8v kf = *(const short8v*)(kb + (g * 16 + lrow) * 64 + uoff);
                sc[g] = mfma16(qf[kc], kf, sc[g]);
            }
        }
        if (t < TA - 1) {
#pragma unroll
            for (int g = 0; g < 8; ++g)
#pragma unroll
                for (int i = 0; i < 4; ++i) ls4[i] += EXP2(sc[g][i]);
        } else {
            int c0 = t * 128;
#pragma unroll
            for (int g = 0; g < 8; ++g)
#pragma unroll
                for (int i = 0; i < 4; ++i) {
                    float sv = (c0 + g * 16 + lrow > r0 + lseg * 4 + i) ? -1e30f : sc[g][i];
                    ls4[i] += EXP2(sv);
                }
        }
        FENCE; BARRIER;
    }
#pragma unroll
    for (int off = 1; off < 16; off <<= 1)
#pragma unroll
        for (int i = 0; i < 4; ++i) ls4[i] += __shfl_xor(ls4[i], off, 64);
    float invl[4];
#pragma unroll
    for (int i = 0; i < 4; ++i) invl[i] = 1.0f / ls4[i];

    // ---------------- pass B: probs + PV over 64-col tiles -------------------------
    auto STAGEKB = [&](int buf, int t) {
        const size_t kbase = ((size_t)b * 2048 + (size_t)t * 64) * 3072 + 1024 + h * 64;
        int c = tid >> 3, u = tid & 7, us = u ^ (c & 7);
        gload16(QKVB + kbase + (size_t)c * 3072 + us * 8, &KV[buf][(tid & ~63) * 8]);
    };
    auto STAGEVB = [&](int buf, int t) {
        const size_t vbase = (size_t)bh * 64 * 2048 + (size_t)t * 64;
        int e = tid >> 3, u = tid & 7, us = u ^ (e & 7);
        gload16(VT + vbase + (size_t)e * 2048 + us * 8, &KV[buf][4096 + (tid & ~63) * 8]);
    };

    float* ab = ATTN + ((size_t)bh * 2048 + r0) * 2048;
    f32x4 zacc[4];
#pragma unroll
    for (int i = 0; i < 4; ++i) zacc[i] = (f32x4){0.f, 0.f, 0.f, 0.f};

    STAGEKB(0, 0); STAGEVB(0, 0);
    for (int t = 0; t < T; ++t) {
        if (t < T - 1) { STAGEKB((t + 1) & 1, t + 1); STAGEVB((t + 1) & 1, t + 1); WAITVM2; }
        else WAITVM0;
        BARRIER;
        if (t < Tw) {
            const unsigned short* kb = KV[t & 1];
            const unsigned short* vb = KV[t & 1] + 4096;
            int c0 = t * 64;
            f32x4 sc[4];
#pragma unroll
            for (int g = 0; g < 4; ++g) sc[g] = (f32x4){0.f, 0.f, 0.f, 0.f};
#pragma unroll
            for (int kc = 0; kc < 2; ++kc) {
                int uoff = (((kc * 4 + lseg) ^ (lrow & 7)) << 3);
#pragma unroll
                for (int g = 0; g < 4; ++g) {
                    short8v kf = *(const short8v*)(kb + (g * 16 + lrow) * 64 + uoff);
                    sc[g] = mfma16(qf[kc], kf, sc[g]);
                }
            }
            if (t < Tw - 1) {
#pragma unroll
                for (int g = 0; g < 4; ++g)
#pragma unroll
                    for (int i = 0; i < 4; ++i)
                        Pl[w][lseg * 4 + i][g * 16 + lrow] = EXP2(sc[g][i]) * invl[i];
            } else {
#pragma unroll
                for (int g = 0; g < 4; ++g)
#pragma unroll
                    for (int i = 0; i < 4; ++i) {
                        float sv = (c0 + g * 16 + lrow > r0 + lseg * 4 + i) ? -1e30f : sc[g][i];
                        Pl[w][lseg * 4 + i][g * 16 + lrow] = EXP2(sv) * invl[i];
                    }
            }
            // A-fragments for PV (v_cvt_pk_bf16_f32: 2 f32 -> packed 2x bf16)
            short8v pf[2];
#pragma unroll
            for (int kc = 0; kc < 2; ++kc) {
                f32x4 p0 = *(const f32x4*)&Pl[w][lrow][kc * 32 + lseg * 8];
                f32x4 p1 = *(const f32x4*)&Pl[w][lrow][kc * 32 + lseg * 8 + 4];
                union { uint32_t u[4]; short8v s; } pu;
                pu.u[0] = cvtpk(p0[0], p0[1]);
                pu.u[1] = cvtpk(p0[2], p0[3]);
                pu.u[2] = cvtpk(p1[0], p1[1]);
                pu.u[3] = cvtpk(p1[2], p1[3]);
                pf[kc] = pu.s;
            }
#pragma unroll
            for (int kc = 0; kc < 2; ++kc) {
                int uoff = (((kc * 4 + lseg) ^ (lrow & 7)) << 3);
#pragma unroll
                for (int et = 0; et < 4; ++et) {
                    short8v vf = *(const short8v*)(vb + (et * 16 + lrow) * 64 + uoff);
                    zacc[et] = mfma16(pf[kc], vf, zacc[et]);
                }
            }
            // prob store: 16-lane groups write 256B contiguous runs, nontemporal
            {
                int row4 = lane >> 4, cq = lane & 15;
#pragma unroll
                for (int r4 = 0; r4 < 4; ++r4) {
                    int row = r4 * 4 + row4;
                    ntstore4(ab + (size_t)row * 2048 + c0 + cq * 4,
                             *(const f32x4*)(&Pl[w][row][cq * 4]));
                }
            }
        }
        FENCE; BARRIER;
    }

    // z epilogue (bf16, token-major)
#pragma unroll
    for (int et = 0; et < 4; ++et)
#pragma unroll
        for (int i = 0; i < 4; ++i)
            Z[(size_t)(b * 2048 + r0 + lseg * 4 + i) * 1024 + h * 64 + et * 16 + lrow] =
                f2bf(zacc[et][i]);

    // zero-fill masked tail (per wave, nontemporal 1KB runs)
    int czw = Tw * 64;
    const f32x4 zz = (f32x4){0.f, 0.f, 0.f, 0.f};
    for (int r = 0; r < 16; ++r) {
        float* rp = ab + (size_t)r * 2048;
        for (int c = czw + (lane << 2); c < 2048; c += 256)
            ntstore4(rp + c, zz);
    }
}

// ---------------- launcher ---------------------------------------------------------
extern "C" void kernel_launch(void* const* d_in, const int* in_sizes, int n_in,
                              void* d_out, int out_size, void* d_ws, size_t ws_size,
                              hipStream_t stream) {
    const float* X    = (const float*)d_in[0];   // (2,2048,1024)
    const float* Wqkv = (const float*)d_in[1];   // (3072,1024)
    const float* Bqkv = (const float*)d_in[2];   // (3072,)
    const float* Wout = (const float*)d_in[3];   // (1024,1024)
    const float* Bout = (const float*)d_in[4];   // (1024,)
    float* out  = (float*)d_out;                 // (2,2048,1024)
    float* attn = out + (size_t)4096 * 1024;     // (2,16,2048,2048)

    char* ws = (char*)d_ws;
    unsigned short* QKVB = (unsigned short*)ws; ws += (size_t)4096 * 3072 * 2;
    unsigned short* VTp  = (unsigned short*)ws; ws += (size_t)32 * 64 * 2048 * 2;
    unsigned short* ZBp  = (unsigned short*)ws; ws += (size_t)4096 * 1024 * 2;
    unsigned short* XBp  = (unsigned short*)ws; ws += (size_t)4096 * 1024 * 2;
    unsigned short* WQBp = (unsigned short*)ws; ws += (size_t)3072 * 1024 * 2;
    unsigned short* WOBp = (unsigned short*)ws; ws += (size_t)1024 * 1024 * 2;

    const int na4 = 4096 * 1024 / 4, nb4 = 3072 * 1024 / 4, nc4 = 1024 * 1024 / 4;
    k_cvt3<<<(na4 + nb4 + nc4 + 255) / 256, 256, 0, stream>>>(
        X, XBp, na4, Wqkv, WQBp, nb4, Wout, WOBp, nc4);
    k_gemm_qkv<<<dim3(32, 24), 256, 0, stream>>>(XBp, WQBp, Bqkv, QKVB, VTp);
    k_attn<<<512, 512, 0, stream>>>(QKVB, VTp, attn, ZBp);
    k_gemm_out<<<dim3(32, 8), 256, 0, stream>>>(ZBp, WOBp, Bout, out);
}

// Round 14
// 229.873 us; speedup vs baseline: 1.0405x; 1.0405x over previous
//
#include <hip/hip_runtime.h>
#include <stdint.h>

typedef __attribute__((ext_vector_type(4))) float f32x4;
typedef __attribute__((ext_vector_type(8))) short short8v;
typedef __attribute__((ext_vector_type(4))) unsigned short ushort4v;

#define DEV __device__ __forceinline__
#define EXP2 __builtin_amdgcn_exp2f
#define WAITVM0 asm volatile("s_waitcnt vmcnt(0)" ::: "memory")
#define WAITVM2 asm volatile("s_waitcnt vmcnt(2)" ::: "memory")
#define WAITVM4 asm volatile("s_waitcnt vmcnt(4)" ::: "memory")
#define FENCE   asm volatile("" ::: "memory")
#define BARRIER __builtin_amdgcn_s_barrier()

DEV unsigned short f2bf(float x) {
    union { float f; uint32_t u; } v; v.f = x;
    uint32_t r = v.u + 0x7fffu + ((v.u >> 16) & 1u);
    return (unsigned short)(r >> 16);
}
DEV float bf2f(unsigned short h) {
    union { uint32_t u; float f; } v; v.u = ((uint32_t)h) << 16;
    return v.f;
}
DEV uint32_t cvtpk(float lo, float hi) {
    uint32_t r;
    asm("v_cvt_pk_bf16_f32 %0, %1, %2" : "=v"(r) : "v"(lo), "v"(hi));
    return r;
}
DEV f32x4 mfma16(short8v a, short8v b, f32x4 c) {
    return __builtin_amdgcn_mfma_f32_16x16x32_bf16(a, b, c, 0, 0, 0);
}
DEV void gload16(const unsigned short* g, unsigned short* l) {
    __builtin_amdgcn_global_load_lds(
        (const __attribute__((address_space(1))) unsigned int*)g,
        (__attribute__((address_space(3))) unsigned int*)l, 16, 0, 0);
}
DEV void ntstore4(float* p, f32x4 v) { __builtin_nontemporal_store(v, (f32x4*)p); }

// ---------------- prep: fp32 -> bf16 (all three inputs, one launch) ----------------
__global__ void k_cvt3(const float* __restrict__ a, unsigned short* __restrict__ oa, int na4,
                       const float* __restrict__ b, unsigned short* __restrict__ ob, int nb4,
                       const float* __restrict__ c, unsigned short* __restrict__ oc, int nc4) {
    int i = blockIdx.x * blockDim.x + threadIdx.x;
    const float* in; unsigned short* out; int idx;
    if (i < na4) { in = a; out = oa; idx = i; }
    else if (i < na4 + nb4) { in = b; out = ob; idx = i - na4; }
    else { idx = i - na4 - nb4; if (idx >= nc4) return; in = c; out = oc; }
    f32x4 v = *(const f32x4*)(in + (size_t)idx * 4);
    ushort4v h;
#pragma unroll
    for (int j = 0; j < 4; ++j) h[j] = f2bf(v[j]);
    *(ushort4v*)(out + (size_t)idx * 4) = h;
}

// ---------------- m97-style bf16 GEMM core (128x128 tile, gload_lds, dbuf) ---------
template <int KDIM>
DEV void gemm_core(const unsigned short* __restrict__ APTR,
                   const unsigned short* __restrict__ BPTR,
                   f32x4 (&acc)[4][4]) {
    __shared__ __align__(16) unsigned short As[2][128 * 32], Bs[2][128 * 32];
    int tid = threadIdx.x, lane = tid & 63, w = tid >> 6;
    int bm = blockIdx.x, bn = blockIdx.y;
    int wr = (w >> 1) * 64, wc = (w & 1) * 64;
    int lrow = lane & 15, lseg = lane >> 4;
#pragma unroll
    for (int m = 0; m < 4; ++m)
#pragma unroll
        for (int n = 0; n < 4; ++n) acc[m][n] = (f32x4){0.f, 0.f, 0.f, 0.f};
    auto STAGE = [&](int buf, int k0) {
#pragma unroll
        for (int i = 0; i < 2; ++i) {
            int ch = i * 256 + tid;
            int row = ch >> 2, seg = ch & 3;
            gload16(APTR + (size_t)(bm * 128 + row) * KDIM + k0 + seg * 8,
                    &As[buf][(i * 256 + (tid & ~63)) * 8]);
            gload16(BPTR + (size_t)(bn * 128 + row) * KDIM + k0 + seg * 8,
                    &Bs[buf][(i * 256 + (tid & ~63)) * 8]);
        }
    };
    const int NT = KDIM / 32;
    STAGE(0, 0);
    for (int t = 0; t < NT; ++t) {
        if (t < NT - 1) { STAGE((t + 1) & 1, (t + 1) * 32); WAITVM4; } else WAITVM0;
        BARRIER;
        const unsigned short* as = As[t & 1];
        const unsigned short* bs = Bs[t & 1];
        short8v fa[4], fb[4];
#pragma unroll
        for (int m = 0; m < 4; ++m) {
            fa[m] = *(const short8v*)(as + (wr + m * 16 + lrow) * 32 + lseg * 8);
            fb[m] = *(const short8v*)(bs + (wc + m * 16 + lrow) * 32 + lseg * 8);
        }
#pragma unroll
        for (int m = 0; m < 4; ++m)
#pragma unroll
            for (int n = 0; n < 4; ++n)
                acc[m][n] = mfma16(fa[m], fb[n], acc[m][n]);
        FENCE; BARRIER;
    }
}

// ---------------- K1: qkv = x @ Wqkv^T + b  (bf16 out) -----------------------------
__global__ __launch_bounds__(256) void k_gemm_qkv(
    const unsigned short* __restrict__ XB, const unsigned short* __restrict__ WB,
    const float* __restrict__ BIAS, unsigned short* __restrict__ QKVB) {
    f32x4 acc[4][4];
    gemm_core<1024>(XB, WB, acc);
    int tid = threadIdx.x, lane = tid & 63, w = tid >> 6;
    int bm = blockIdx.x, bn = blockIdx.y;
    int wr = (w >> 1) * 64, wc = (w & 1) * 64;
    int lrow = lane & 15, lseg = lane >> 4;
    const int N = 3072;
#pragma unroll
    for (int n = 0; n < 4; ++n) {
        int col = bn * 128 + wc + n * 16 + lrow;
        float bv = BIAS[col];
#pragma unroll
        for (int m = 0; m < 4; ++m) {
            int row = bm * 128 + wr + m * 16 + lseg * 4;
#pragma unroll
            for (int i = 0; i < 4; ++i)
                QKVB[(size_t)(row + i) * N + col] = f2bf(acc[m][n][i] + bv);
        }
    }
}

// ---------------- K3: out = z @ Wout^T + b (fp32 out, nt stores) -------------------
__global__ __launch_bounds__(256) void k_gemm_out(
    const unsigned short* __restrict__ ZB, const unsigned short* __restrict__ WOB,
    const float* __restrict__ BIAS, float* __restrict__ OUT) {
    f32x4 acc[4][4];
    gemm_core<1024>(ZB, WOB, acc);
    int tid = threadIdx.x, lane = tid & 63, w = tid >> 6;
    int bm = blockIdx.x, bn = blockIdx.y;
    int wr = (w >> 1) * 64, wc = (w & 1) * 64;
    int lrow = lane & 15, lseg = lane >> 4;
    const int N = 1024;
#pragma unroll
    for (int n = 0; n < 4; ++n) {
        int col = bn * 128 + wc + n * 16 + lrow;
        float bv = BIAS[col];
#pragma unroll
        for (int m = 0; m < 4; ++m) {
            int row = bm * 128 + wr + m * 16 + lseg * 4;
#pragma unroll
            for (int i = 0; i < 4; ++i)
                __builtin_nontemporal_store(acc[m][n][i] + bv,
                                            OUT + (size_t)(row + i) * N + col);
        }
    }
}

// ---------------- prep V^T (bf16 [bh][e][c]) from qkv bf16 -------------------------
__global__ void k_prep_v(const unsigned short* __restrict__ QKVB, unsigned short* __restrict__ VT) {
    __shared__ unsigned short vt[32][72];
    int bh = blockIdx.y, b = bh >> 4, h = bh & 15;
    int c0 = blockIdx.x * 32;
    int t = threadIdx.x;
    int c = t >> 3, e8 = (t & 7) * 8;
    *(short8v*)&vt[c][e8] =
        *(const short8v*)(QKVB + (size_t)(b * 2048 + c0 + c) * 3072 + 2048 + h * 64 + e8);
    __syncthreads();
    int e = t & 63, cg = t >> 6;
    unsigned short tmp[8];
#pragma unroll
    for (int i = 0; i < 8; ++i) tmp[i] = vt[cg * 8 + i][e];
    *(short8v*)(VT + ((size_t)bh * 64 + e) * 2048 + c0 + cg * 8) = *(short8v*)tmp;
}

// ---------------- K2: fused causal attention (8 waves, 128 rows/block) -------------
// pass A: 128-col K tiles (2x16KB dbuf); pass B: 64-col K+V tiles in same 32KB LDS
__global__ __launch_bounds__(512) void k_attn(
    const unsigned short* __restrict__ QKVB, const unsigned short* __restrict__ VT,
    float* __restrict__ ATTN, unsigned short* __restrict__ Z) {
    __shared__ __align__(16) unsigned short KV[2][8192];     // A: K[128][64]; B: K[64][64]+V[64][64]
    __shared__ __align__(16) float Pl[8][16][68];            // per-wave P relayout

    const float SCALE = 0.18033688011112042f;  // log2(e)/8 ; softmax in base-2
    int blk = blockIdx.x;
    int bh = blk & 31;
    int rtp = blk >> 5;                        // 0..15
    int rt = (rtp < 8) ? (15 - rtp) : (rtp - 8);  // heavy/light interleave for balance
    int b = bh >> 4, h = bh & 15;
    int tid = threadIdx.x, lane = tid & 63, w = tid >> 6;
    int lrow = lane & 15, lseg = lane >> 4;
    int r0 = rt * 128 + w * 16;
    int T = 2 * rt + 2;                        // pass-B 64-col tiles
    int Tw = (r0 >> 6) + 1;                    // this wave's causal 64-col tile count

    // Q fragments (bf16, rescaled by SCALE): A[m=r0+lrow][k=kc*32+lseg*8+j]
    short8v qf[2];
    {
        const unsigned short* qp =
            QKVB + (size_t)(b * 2048 + r0 + lrow) * 3072 + h * 64 + lseg * 8;
#pragma unroll
        for (int kc = 0; kc < 2; ++kc) {
            short8v qr = *(const short8v*)(qp + kc * 32);
            short8v qs;
#pragma unroll
            for (int j = 0; j < 8; ++j)
                qs[j] = (short)f2bf(bf2f((unsigned short)qr[j]) * SCALE);
            qf[kc] = qs;
        }
    }

    // ---------------- pass A: row sums over 128-col tiles --------------------------
    auto STAGEKA = [&](int buf, int t) {       // 128 keys x 64e
        const size_t kbase = ((size_t)b * 2048 + (size_t)t * 128) * 3072 + 1024 + h * 64;
#pragma unroll
        for (int i2 = 0; i2 < 2; ++i2) {
            int ch = i2 * 512 + tid;
            int c = ch >> 3, u = ch & 7, us = u ^ (c & 7);
            gload16(QKVB + kbase + (size_t)c * 3072 + us * 8,
                    &KV[buf][(i2 * 512 + (tid & ~63)) * 8]);
        }
    };
    float ls4[4] = {0.f, 0.f, 0.f, 0.f};
    int TA = rt + 1;
    STAGEKA(0, 0);
    for (int t = 0; t < TA; ++t) {
        if (t < TA - 1) { STAGEKA((t + 1) & 1, t + 1); WAITVM2; } else WAITVM0;
        BARRIER;
        const unsigned short* kb = KV[t & 1];
        f32x4 sc[8];
#pragma unroll
        for (int g = 0; g < 8; ++g) sc[g] = (f32x4){0.f, 0.f, 0.f, 0.f};
#pragma unroll
        for (int kc = 0; kc < 2; ++kc) {
            int uoff = (((kc * 4 + lseg) ^ (lrow & 7)) << 3);
#pragma unroll
            for (int g = 0; g < 8; ++g) {
                short8v kf = *(const short8v*)(kb + (g * 16 + lrow) * 64 + uoff);
                sc[g] = mfma16(qf[kc], kf, sc[g]);
            }
        }
        if (t < TA - 1) {
#pragma unroll
            for (int g = 0; g < 8; ++g)
#pragma unroll
                for (int i = 0; i < 4; ++i) ls4[i] += EXP2(sc[g][i]);
        } else {
            int c0 = t * 128;
#pragma unroll
            for (int g = 0; g < 8; ++g)
#pragma unroll
                for (int i = 0; i < 4; ++i) {
                    float sv = (c0 + g * 16 + lrow > r0 + lseg * 4 + i) ? -1e30f : sc[g][i];
                    ls4[i] += EXP2(sv);
                }
        }
        FENCE; BARRIER;
    }
#pragma unroll
    for (int off = 1; off < 16; off <<= 1)
#pragma unroll
        for (int i = 0; i < 4; ++i) ls4[i] += __shfl_xor(ls4[i], off, 64);
    float invl[4];
#pragma unroll
    for (int i = 0; i < 4; ++i) invl[i] = 1.0f / ls4[i];

    // ---------------- pass B: probs + PV over 64-col tiles -------------------------
    auto STAGEKB = [&](int buf, int t) {
        const size_t kbase = ((size_t)b * 2048 + (size_t)t * 64) * 3072 + 1024 + h * 64;
        int c = tid >> 3, u = tid & 7, us = u ^ (c & 7);
        gload16(QKVB + kbase + (size_t)c * 3072 + us * 8, &KV[buf][(tid & ~63) * 8]);
    };
    auto STAGEVB = [&](int buf, int t) {
        const size_t vbase = (size_t)bh * 64 * 2048 + (size_t)t * 64;
        int e = tid >> 3, u = tid & 7, us = u ^ (e & 7);
        gload16(VT + vbase + (size_t)e * 2048 + us * 8, &KV[buf][4096 + (tid & ~63) * 8]);
    };

    float* ab = ATTN + ((size_t)bh * 2048 + r0) * 2048;
    f32x4 zacc[4];
#pragma unroll
    for (int i = 0; i < 4; ++i) zacc[i] = (f32x4){0.f, 0.f, 0.f, 0.f};

    STAGEKB(0, 0); STAGEVB(0, 0);
    for (int t = 0; t < T; ++t) {
        if (t < T - 1) { STAGEKB((t + 1) & 1, t + 1); STAGEVB((t + 1) & 1, t + 1); WAITVM2; }
        else WAITVM0;
        BARRIER;
        if (t < Tw) {
            const unsigned short* kb = KV[t & 1];
            const unsigned short* vb = KV[t & 1] + 4096;
            int c0 = t * 64;
            f32x4 sc[4];
#pragma unroll
            for (int g = 0; g < 4; ++g) sc[g] = (f32x4){0.f, 0.f, 0.f, 0.f};
#pragma unroll
            for (int kc = 0; kc < 2; ++kc) {
                int uoff = (((kc * 4 + lseg) ^ (lrow & 7)) << 3);
#pragma unroll
                for (int g = 0; g < 4; ++g) {
                    short8v kf = *(const short8v*)(kb + (g * 16 + lrow) * 64 + uoff);
                    sc[g] = mfma16(qf[kc], kf, sc[g]);
                }
            }
            if (t < Tw - 1) {
#pragma unroll
                for (int g = 0; g < 4; ++g)
#pragma unroll
                    for (int i = 0; i < 4; ++i)
                        Pl[w][lseg * 4 + i][g * 16 + lrow] = EXP2(sc[g][i]) * invl[i];
            } else {
#pragma unroll
                for (int g = 0; g < 4; ++g)
#pragma unroll
                    for (int i = 0; i < 4; ++i) {
                        float sv = (c0 + g * 16 + lrow > r0 + lseg * 4 + i) ? -1e30f : sc[g][i];
                        Pl[w][lseg * 4 + i][g * 16 + lrow] = EXP2(sv) * invl[i];
                    }
            }
            // A-fragments for PV (v_cvt_pk_bf16_f32: 2 f32 -> packed 2x bf16)
            short8v pf[2];
#pragma unroll
            for (int kc = 0; kc < 2; ++kc) {
                f32x4 p0 = *(const f32x4*)&Pl[w][lrow][kc * 32 + lseg * 8];
                f32x4 p1 = *(const f32x4*)&Pl[w][lrow][kc * 32 + lseg * 8 + 4];
                union { uint32_t u[4]; short8v s; } pu;
                pu.u[0] = cvtpk(p0[0], p0[1]);
                pu.u[1] = cvtpk(p0[2], p0[3]);
                pu.u[2] = cvtpk(p1[0], p1[1]);
                pu.u[3] = cvtpk(p1[2], p1[3]);
                pf[kc] = pu.s;
            }
#pragma unroll
            for (int kc = 0; kc < 2; ++kc) {
                int uoff = (((kc * 4 + lseg) ^ (lrow & 7)) << 3);
#pragma unroll
                for (int et = 0; et < 4; ++et) {
                    short8v vf = *(const short8v*)(vb + (et * 16 + lrow) * 64 + uoff);
                    zacc[et] = mfma16(pf[kc], vf, zacc[et]);
                }
            }
            // prob store: 16-lane groups write 256B contiguous runs, nontemporal
            {
                int row4 = lane >> 4, cq = lane & 15;
#pragma unroll
                for (int r4 = 0; r4 < 4; ++r4) {
                    int row = r4 * 4 + row4;
                    ntstore4(ab + (size_t)row * 2048 + c0 + cq * 4,
                             *(const f32x4*)(&Pl[w][row][cq * 4]));
                }
            }
        }
        FENCE; BARRIER;
    }

    // z epilogue (bf16, token-major)
#pragma unroll
    for (int et = 0; et < 4; ++et)
#pragma unroll
        for (int i = 0; i < 4; ++i)
            Z[(size_t)(b * 2048 + r0 + lseg * 4 + i) * 1024 + h * 64 + et * 16 + lrow] =
                f2bf(zacc[et][i]);

    // zero-fill masked tail (per wave, nontemporal 1KB runs)
    int czw = Tw * 64;
    const f32x4 zz = (f32x4){0.f, 0.f, 0.f, 0.f};
    for (int r = 0; r < 16; ++r) {
        float* rp = ab + (size_t)r * 2048;
        for (int c = czw + (lane << 2); c < 2048; c += 256)
            ntstore4(rp + c, zz);
    }
}

// ---------------- launcher ---------------------------------------------------------
extern "C" void kernel_launch(void* const* d_in, const int* in_sizes, int n_in,
                              void* d_out, int out_size, void* d_ws, size_t ws_size,
                              hipStream_t stream) {
    const float* X    = (const float*)d_in[0];   // (2,2048,1024)
    const float* Wqkv = (const float*)d_in[1];   // (3072,1024)
    const float* Bqkv = (const float*)d_in[2];   // (3072,)
    const float* Wout = (const float*)d_in[3];   // (1024,1024)
    const float* Bout = (const float*)d_in[4];   // (1024,)
    float* out  = (float*)d_out;                 // (2,2048,1024)
    float* attn = out + (size_t)4096 * 1024;     // (2,16,2048,2048)

    char* ws = (char*)d_ws;
    unsigned short* QKVB = (unsigned short*)ws; ws += (size_t)4096 * 3072 * 2;
    unsigned short* VTp  = (unsigned short*)ws; ws += (size_t)32 * 64 * 2048 * 2;
    unsigned short* ZBp  = (unsigned short*)ws; ws += (size_t)4096 * 1024 * 2;
    unsigned short* XBp  = (unsigned short*)ws; ws += (size_t)4096 * 1024 * 2;
    unsigned short* WQBp = (unsigned short*)ws; ws += (size_t)3072 * 1024 * 2;
    unsigned short* WOBp = (unsigned short*)ws; ws += (size_t)1024 * 1024 * 2;

    const int na4 = 4096 * 1024 / 4, nb4 = 3072 * 1024 / 4, nc4 = 1024 * 1024 / 4;
    k_cvt3<<<(na4 + nb4 + nc4 + 255) / 256, 256, 0, stream>>>(
        X, XBp, na4, Wqkv, WQBp, nb4, Wout, WOBp, nc4);
    k_gemm_qkv<<<dim3(32, 24), 256, 0, stream>>>(XBp, WQBp, Bqkv, QKVB);
    k_prep_v<<<dim3(64, 32), 256, 0, stream>>>(QKVB, VTp);
    k_attn<<<512, 512, 0, stream>>>(QKVB, VTp, attn, ZBp);
    k_gemm_out<<<dim3(32, 8), 256, 0, stream>>>(ZBp, WOBp, Bout, out);
}